// Round 7
// baseline (137.133 us; speedup 1.0000x reference)
//
#include <hip/hip_runtime.h>
#include <hip/hip_bf16.h>

// SelfAttentionTransformer: B=4, L=2048, D=256, H=8, dk=32, F=1024
// f32 inputs / f32 output. Round 14:
//  - k_ffn rebuilt: ROLLED chunk loop (I-cache resident body, ~1.5 KB) and
//    W1+W2 both 2-deep, staged 2 chunks ahead (cover ~1.7 chunks each),
//    uniform vmcnt(24) waits, b1 in LDS (no VMEM in loop), clamped tail stages.
//  - k_prep / k_scores / k_av unchanged.

#define B_ 4
#define L_ 2048
#define D_ 256
#define F_ 1024
#define PI_F 3.14159265358979323846f

typedef __bf16 bf16x8 __attribute__((ext_vector_type(8)));
typedef float floatx4 __attribute__((ext_vector_type(4)));
typedef unsigned short ushortx4 __attribute__((ext_vector_type(4)));
typedef unsigned short ushortx8 __attribute__((ext_vector_type(8)));

#define WAIT_VM(n) asm volatile("s_waitcnt vmcnt(" #n ")" ::: "memory")
#define WAIT_LGKM() asm volatile("s_waitcnt lgkmcnt(0)" ::: "memory")
#define SCHED0() __builtin_amdgcn_sched_barrier(0)
#define BARRIER() do { SCHED0(); __builtin_amdgcn_s_barrier(); SCHED0(); } while (0)

__device__ __forceinline__ unsigned short f2bf(float f) {
    unsigned int u = __float_as_uint(f);
    u = (u + 0x7FFFu + ((u >> 16) & 1u)) >> 16;   // RNE
    return (unsigned short)u;
}
__device__ __forceinline__ float bf2f(unsigned short u) {
    union { unsigned int i; float f; } v; v.i = ((unsigned int)u) << 16; return v.f;
}

__device__ __forceinline__ void async_cp16(unsigned short* lds, const unsigned short* g) {
    __builtin_amdgcn_global_load_lds(
        (const __attribute__((address_space(1))) unsigned int*)g,
        (__attribute__((address_space(3))) unsigned int*)lds, 16, 0, 0);
}

// ---------------- prep, compact 1D grid (2817 blocks) ----------------
__global__ __launch_bounds__(256) void k_prep(const float* __restrict__ x,
                                              const float* __restrict__ W1,
                                              const float* __restrict__ W2,
                                              const int* __restrict__ mask,
                                              unsigned short* __restrict__ mb,
                                              unsigned short* __restrict__ XmT,
                                              unsigned short* __restrict__ W1T,
                                              unsigned short* __restrict__ W2T) {
    __shared__ float tile[32][33];
    int r = blockIdx.x, t = threadIdx.x;
    if (r >= 2560) {
        if (r < 2816) {
            int idx = (r - 2560) * 256 + t;   // 0..65535
            int l = idx >> 5, k = idx & 31;
            float s = 0.f;
#pragma unroll
            for (int b = 0; b < B_; b++) {
                const float* xp = x + ((size_t)(b * L_ + l)) * D_ + k;
#pragma unroll
                for (int h = 0; h < 8; h++) s += xp[h * 32];
            }
            mb[idx] = f2bf(s * (1.f / 32.f));
        } else {
#pragma unroll
            for (int c = 0; c < 32; c++) {
                int e = c * 256 + t;          // 0..8191
                int b = e >> 11, j = e & (L_ - 1);
                XmT[(size_t)(1024 + b) * L_ + j] = mask[b * L_ + j] ? 0x3F80 : 0;
            }
        }
        return;
    }
    const float* in; unsigned short* outp; int R, C; const int* mrow = nullptr; size_t bo = 0;
    int bx, by;
    if (r < 2048) {
        int z = r >> 9, rem = r & 511; by = rem >> 3; bx = rem & 7;
        in = x; outp = XmT; R = L_; C = 256; bo = (size_t)z * R * C; mrow = mask + z * L_;
    } else if (r < 2304) {
        int rem = r - 2048; bx = rem & 31; by = rem >> 5;
        in = W1; outp = W1T; R = 256; C = 1024;
    } else {
        int rem = r - 2304; bx = rem & 7; by = rem >> 3;
        in = W2; outp = W2T; R = 1024; C = 256;
    }
    int r0 = by * 32, c0 = bx * 32;
    int tx = t & 31, ty = t >> 5;
#pragma unroll
    for (int rr = 0; rr < 4; rr++) {
        int rw = ty + rr * 8;
        tile[rw][tx] = in[bo + (size_t)(r0 + rw) * C + c0 + tx];
    }
    float mfac = 1.f;
    if (mrow) mfac = mrow[r0 + tx] ? 1.f : 0.f;
    __syncthreads();
#pragma unroll
    for (int rr = 0; rr < 4; rr++) {
        int c = ty + rr * 8;
        outp[bo + (size_t)(c0 + c) * R + r0 + tx] = f2bf(tile[tx][c] * mfac);
    }
}

// ---------------- E = exp(sin^2(0.5*clip(m.mT))) via MFMA, bf16 out ----------------
__global__ __launch_bounds__(256) void k_scores_mfma(const unsigned short* __restrict__ mb,
                                                     unsigned short* __restrict__ E) {
    const int t = threadIdx.x, lane = t & 63, wid = t >> 6;
    const int wm = (wid >> 1) * 64, wn = (wid & 1) * 32;
    const int lr = lane & 15, lq = lane >> 4;
    int m0 = blockIdx.y * 128, n0 = blockIdx.x * 64;
    bf16x8 af[4], bfr[2];
#pragma unroll
    for (int i = 0; i < 4; i++)
        af[i] = *(const bf16x8*)(mb + (size_t)(m0 + wm + i * 16 + lr) * 32 + lq * 8);
#pragma unroll
    for (int j = 0; j < 2; j++)
        bfr[j] = *(const bf16x8*)(mb + (size_t)(n0 + wn + j * 16 + lr) * 32 + lq * 8);
    floatx4 acc[4][2];
#pragma unroll
    for (int i = 0; i < 4; i++)
#pragma unroll
        for (int j = 0; j < 2; j++) {
            acc[i][j] = (floatx4){0.f, 0.f, 0.f, 0.f};
            acc[i][j] = __builtin_amdgcn_mfma_f32_16x16x32_bf16(af[i], bfr[j], acc[i][j], 0, 0, 0);
        }
#pragma unroll
    for (int i = 0; i < 4; i++)
#pragma unroll
        for (int j = 0; j < 2; j++)
#pragma unroll
            for (int r = 0; r < 4; r++) {
                int row = m0 + wm + i * 16 + lq * 4 + r;
                int col = n0 + wn + j * 16 + lr;
                float d = fminf(fmaxf(acc[i][j][r], -PI_F), PI_F);
                float sn = __sinf(0.5f * d);
                E[(size_t)row * L_ + col] = f2bf(__expf(sn * sn));
            }
}

// ---------------- AV: C[2048,1088] = E @ XmT^T (bf16 out), 3-deep counted-vmcnt ----------------
__global__ __launch_bounds__(256) void k_av(const unsigned short* __restrict__ E,
                                            const unsigned short* __restrict__ XmT,
                                            unsigned short* __restrict__ Cb) {
    __shared__ __align__(16) unsigned short sbuf[3][128 * 64 + 64 * 64];
    const int t = threadIdx.x, lane = t & 63, wid = t >> 6;
    const int wm = (wid >> 1) * 64, wn = (wid & 1) * 32;
    const int lr = lane & 15, lq = lane >> 4;
    const int lrow = lane >> 3, lseg = lane & 7;

    int bid = blockIdx.x;
    int swz = (bid & 7) * 34 + (bid >> 3);
    int m0 = (swz / 17) * 128, n0 = (swz % 17) * 64;

    const unsigned short* Ag[4]; int sAoff[4];
#pragma unroll
    for (int q = 0; q < 4; q++) {
        int rl = wid * 32 + q * 8 + lrow;
        Ag[q] = E + (size_t)(m0 + rl) * L_ + ((lseg - rl) & 7) * 8;
        sAoff[q] = (wid * 32 + q * 8) * 64;
    }
    const unsigned short* Bg[2]; int sBoff[2];
#pragma unroll
    for (int q = 0; q < 2; q++) {
        int rl = wid * 16 + q * 8 + lrow;
        Bg[q] = XmT + (size_t)(n0 + rl) * L_ + ((lseg - rl) & 7) * 8;
        sBoff[q] = 8192 + (wid * 16 + q * 8) * 64;
    }
    int arot[4], aroff[4], brot[2], broff[2];
#pragma unroll
    for (int i = 0; i < 4; i++) { int ar = wm + i * 16 + lr; aroff[i] = ar * 64; arot[i] = lq + ar; }
#pragma unroll
    for (int j = 0; j < 2; j++) { int br = wn + j * 16 + lr; broff[j] = 8192 + br * 64; brot[j] = lq + br; }

    floatx4 acc[4][2];
#pragma unroll
    for (int i = 0; i < 4; i++)
#pragma unroll
        for (int j = 0; j < 2; j++) acc[i][j] = (floatx4){0.f, 0.f, 0.f, 0.f};

    auto stage = [&](unsigned short* base, int k0) {
#pragma unroll
        for (int q = 0; q < 4; q++) async_cp16(base + sAoff[q], Ag[q] + k0);
#pragma unroll
        for (int q = 0; q < 2; q++) async_cp16(base + sBoff[q], Bg[q] + k0);
    };
    auto compute = [&](const unsigned short* base) {
#pragma unroll
        for (int s = 0; s < 2; s++) {
            bf16x8 af[4], bfr[2];
#pragma unroll
            for (int i = 0; i < 4; i++)
                af[i] = *(const bf16x8*)(base + aroff[i] + ((s * 4 + arot[i]) & 7) * 8);
#pragma unroll
            for (int j = 0; j < 2; j++)
                bfr[j] = *(const bf16x8*)(base + broff[j] + ((s * 4 + brot[j]) & 7) * 8);
#pragma unroll
            for (int i = 0; i < 4; i++)
#pragma unroll
                for (int j = 0; j < 2; j++)
                    acc[i][j] = __builtin_amdgcn_mfma_f32_16x16x32_bf16(af[i], bfr[j], acc[i][j], 0, 0, 0);
        }
    };

    unsigned short *p0 = sbuf[0], *p1 = sbuf[1], *p2 = sbuf[2];
    stage(p0, 0); stage(p1, 64); stage(p2, 128);
    WAIT_VM(12); BARRIER();
    for (int p = 0; p < 29; ++p) {
        compute(p0);
        BARRIER();
        stage(p0, (p + 3) << 6);
        WAIT_VM(12); BARRIER();
        unsigned short* tmp = p0; p0 = p1; p1 = p2; p2 = tmp;
    }
    compute(p0);
    BARRIER();
    WAIT_VM(6); BARRIER();
    compute(p1);
    BARRIER();
    WAIT_VM(0); BARRIER();
    compute(p2);

#pragma unroll
    for (int i = 0; i < 4; i++)
#pragma unroll
        for (int j = 0; j < 2; j++)
#pragma unroll
            for (int r = 0; r < 4; r++) {
                int row = m0 + wm + i * 16 + lq * 4 + r;
                int col = n0 + wn + j * 16 + lr;
                Cb[(size_t)row * 1088 + col] = f2bf(acc[i][j][r]);
            }
}

// ---------------- k_ffn: out = LN2( h + relu(h@W1+b1)@W2 + b2 ),  h = LN1(x + C/rs)
//                  256 blocks x 32 tokens; rolled loop, W1/W2 2-deep staged 2-ahead ----------------
__global__ __launch_bounds__(256, 1) void k_ffn(const float* __restrict__ x,
                                                const unsigned short* __restrict__ Cb,
                                                const unsigned short* __restrict__ W1T,
                                                const unsigned short* __restrict__ W2T,
                                                const float* __restrict__ b1,
                                                const float* __restrict__ b2,
                                                const float* __restrict__ g1, const float* __restrict__ be1,
                                                const float* __restrict__ g2, const float* __restrict__ be2,
                                                float* __restrict__ out) {
    __shared__ __align__(16) unsigned short hA[4 * 32 * 64];        // 16 KB
    __shared__ __align__(16) unsigned short W1b[2][4 * 64 * 64];    // 64 KB
    __shared__ __align__(16) unsigned short W2b[2][4 * 64 * 64];    // 64 KB
    __shared__ __align__(16) unsigned short t1c[32 * 72];           // 4.5 KB
    __shared__ float b1s[1024];                                     // 4 KB
    __shared__ float red[4][32][2];                                 // 1 KB    => 153.5 KB

    const int t = threadIdx.x, lane = t & 63, wid = t >> 6;
    const int lr = lane & 15, lq = lane >> 4;
    const int half = lane >> 5, l32 = lane & 31;
    const int m0 = blockIdx.x * 32;
    const int lrow8 = lane >> 3, kk = lane & 7;

    // stage one 64-f chunk of W1 (layout [kc][fl][rot-seg]) -- 8 issues/wave
    auto stageW1 = [&](unsigned short* buf, int fc) {
#pragma unroll
        for (int q = 0; q < 8; q++) {
            int kc = q >> 1, sub = q & 1;
            int fl = sub * 32 + wid * 8 + lrow8;
            const unsigned short* src = W1T + (size_t)(fc * 64 + fl) * 256 + kc * 64 + (((kk - fl) & 7) * 8);
            async_cp16(buf + kc * 4096 + sub * 2048 + wid * 512, src);
        }
    };
    // stage one 64-k chunk of W2 (layout [nc][nl][rot-seg]) -- 8 issues/wave
    auto stageW2 = [&](unsigned short* buf, int fc) {
#pragma unroll
        for (int q = 0; q < 8; q++) {
            int nc = q >> 1, sub = q & 1;
            int nl = sub * 32 + wid * 8 + lrow8;
            const unsigned short* src = W2T + (size_t)(nc * 64 + nl) * 1024 + fc * 64 + (((kk - nl) & 7) * 8);
            async_cp16(buf + nc * 4096 + sub * 2048 + wid * 512, src);
        }
    };

    // prologue stages: order W1(0), W2(0), W1(1), W2(1)
    stageW1(W1b[0], 0);
    stageW2(W2b[0], 0);
    stageW1(W1b[1], 1);
    stageW2(W2b[1], 1);

    // b1 -> LDS
#pragma unroll
    for (int q = 0; q < 4; q++) b1s[q * 256 + t] = b1[q * 256 + t];
    float4 g1a = *(const float4*)(g1 + l32 * 8);
    float4 g1b = *(const float4*)(g1 + l32 * 8 + 4);
    float4 be1a = *(const float4*)(be1 + l32 * 8);
    float4 be1b = *(const float4*)(be1 + l32 * 8 + 4);

    // ---- LN1 phase: h[32][256] -> hA (rotate-swizzled), 2 tokens/wave/iter ----
#pragma unroll
    for (int it = 0; it < 4; it++) {
        int tloc = wid * 8 + it * 2 + half;
        int tok = m0 + tloc;
        int bi = tok >> 11, ii = tok & (L_ - 1);
        float rs = bf2f(Cb[(size_t)ii * 1088 + 1024 + bi]);
        float4 xv0 = *(const float4*)(x + (size_t)tok * D_ + l32 * 8);
        float4 xv1 = *(const float4*)(x + (size_t)tok * D_ + l32 * 8 + 4);
        ushortx8 cv = *(const ushortx8*)(Cb + (size_t)ii * 1088 + bi * 256 + l32 * 8);
        float v[8];
        v[0] = xv0.x + bf2f(cv[0]) / rs; v[1] = xv0.y + bf2f(cv[1]) / rs;
        v[2] = xv0.z + bf2f(cv[2]) / rs; v[3] = xv0.w + bf2f(cv[3]) / rs;
        v[4] = xv1.x + bf2f(cv[4]) / rs; v[5] = xv1.y + bf2f(cv[5]) / rs;
        v[6] = xv1.z + bf2f(cv[6]) / rs; v[7] = xv1.w + bf2f(cv[7]) / rs;
        float s = 0.f, s2 = 0.f;
#pragma unroll
        for (int k = 0; k < 8; k++) { s += v[k]; s2 += v[k] * v[k]; }
#pragma unroll
        for (int o = 1; o < 32; o <<= 1) { s += __shfl_xor(s, o); s2 += __shfl_xor(s2, o); }
        float mu = s * (1.f / 256.f);
        float var = s2 * (1.f / 256.f) - mu * mu;
        float rq = rsqrtf(var + 1e-5f);
        union { bf16x8 v8; unsigned short u[8]; } hv;
        hv.u[0] = f2bf((v[0] - mu) * rq * g1a.x + be1a.x);
        hv.u[1] = f2bf((v[1] - mu) * rq * g1a.y + be1a.y);
        hv.u[2] = f2bf((v[2] - mu) * rq * g1a.z + be1a.z);
        hv.u[3] = f2bf((v[3] - mu) * rq * g1a.w + be1a.w);
        hv.u[4] = f2bf((v[4] - mu) * rq * g1b.x + be1b.x);
        hv.u[5] = f2bf((v[5] - mu) * rq * g1b.y + be1b.y);
        hv.u[6] = f2bf((v[6] - mu) * rq * g1b.z + be1b.z);
        hv.u[7] = f2bf((v[7] - mu) * rq * g1b.w + be1b.w);
        *(bf16x8*)(hA + (l32 >> 3) * 2048 + tloc * 64 + ((((l32 & 7) + tloc) & 7) * 8)) = hv.v8;
    }
    WAIT_VM(0); WAIT_LGKM(); BARRIER();   // hA + b1s published; prologue stages landed; vmcnt = 0

    // ---- hoist h A-fragments to registers ----
    bf16x8 haf[2][8];
#pragma unroll
    for (int i = 0; i < 2; i++)
#pragma unroll
        for (int kc = 0; kc < 4; kc++)
#pragma unroll
            for (int s = 0; s < 2; s++) {
                int row = i * 16 + lr;
                haf[i][kc * 2 + s] = *(const bf16x8*)(hA + kc * 2048 + row * 64 + (((s * 4 + lq + row) & 7) * 8));
            }

    floatx4 acc[2][4];
#pragma unroll
    for (int i = 0; i < 2; i++)
#pragma unroll
        for (int j = 0; j < 4; j++) acc[i][j] = (floatx4){0.f, 0.f, 0.f, 0.f};

    const int wcol = wid * 16 + lr;

    // ---- rolled main loop: 16 chunks, uniform 16 issues + 2x vmcnt(24)/chunk ----
#pragma unroll 1
    for (int c = 0; c < 16; ++c) {
        unsigned short* w1cur = W1b[c & 1];
        unsigned short* w2cur = W2b[c & 1];
        WAIT_VM(24); BARRIER();           // W1(c) complete (oldest 8 of <=32) & published

        floatx4 a1[2] = { (floatx4){0.f,0.f,0.f,0.f}, (floatx4){0.f,0.f,0.f,0.f} };
#pragma unroll
        for (int kc = 0; kc < 4; kc++)
#pragma unroll
            for (int s = 0; s < 2; s++) {
                bf16x8 bfr = *(const bf16x8*)(w1cur + kc * 4096 + wcol * 64 + (((s * 4 + lq + wcol) & 7) * 8));
                a1[0] = __builtin_amdgcn_mfma_f32_16x16x32_bf16(haf[0][kc * 2 + s], bfr, a1[0], 0, 0, 0);
                a1[1] = __builtin_amdgcn_mfma_f32_16x16x32_bf16(haf[1][kc * 2 + s], bfr, a1[1], 0, 0, 0);
            }
        BARRIER();                        // W1b[c&1] free
        stageW1(w1cur, (c + 2) & 15);     // 8 issues (2-ahead; tail clamps, WAR-safe)

        float bv = b1s[c * 64 + wcol];
#pragma unroll
        for (int i = 0; i < 2; i++)
#pragma unroll
            for (int r = 0; r < 4; r++)
                t1c[(i * 16 + lq * 4 + r) * 72 + wcol] = f2bf(fmaxf(a1[i][r] + bv, 0.f));
        WAIT_LGKM();
        WAIT_VM(24); BARRIER();           // W2(c) complete; t1c published

#pragma unroll
        for (int s = 0; s < 2; s++) {
            bf16x8 af0 = *(const bf16x8*)(t1c + lr * 72 + s * 32 + lq * 8);
            bf16x8 af1 = *(const bf16x8*)(t1c + (16 + lr) * 72 + s * 32 + lq * 8);
#pragma unroll
            for (int j = 0; j < 4; j++) {
                int nl = j * 16 + lr;
                bf16x8 bfr = *(const bf16x8*)(w2cur + wid * 4096 + nl * 64 + (((s * 4 + lq + nl) & 7) * 8));
                acc[0][j] = __builtin_amdgcn_mfma_f32_16x16x32_bf16(af0, bfr, acc[0][j], 0, 0, 0);
                acc[1][j] = __builtin_amdgcn_mfma_f32_16x16x32_bf16(af1, bfr, acc[1][j], 0, 0, 0);
            }
        }
        BARRIER();                        // W2b[c&1] + t1c free
        stageW2(w2cur, (c + 2) & 15);     // 8 issues (2-ahead)
    }

    // ---- LN2 epilogue ----
    float psum[2][4], psq[2][4];
#pragma unroll
    for (int i = 0; i < 2; i++)
#pragma unroll
        for (int r = 0; r < 4; r++) { psum[i][r] = 0.f; psq[i][r] = 0.f; }
#pragma unroll
    for (int i = 0; i < 2; i++)
#pragma unroll
        for (int j = 0; j < 4; j++) {
            int col = wid * 64 + j * 16 + lr;
            float bv = b2[col];
            int kc = col >> 6, ks = (col >> 3) & 7, ke = col & 7;
#pragma unroll
            for (int r = 0; r < 4; r++) {
                int row = i * 16 + lq * 4 + r;
                float hres = bf2f(hA[kc * 2048 + row * 64 + (((ks + row) & 7) * 8) + ke]);
                float v = acc[i][j][r] + bv + hres;
                acc[i][j][r] = v;
                psum[i][r] += v; psq[i][r] += v * v;
            }
        }
#pragma unroll
    for (int o = 1; o < 16; o <<= 1)
#pragma unroll
        for (int i = 0; i < 2; i++)
#pragma unroll
            for (int r = 0; r < 4; r++) { psum[i][r] += __shfl_xor(psum[i][r], o); psq[i][r] += __shfl_xor(psq[i][r], o); }
    if (lr == 0) {
#pragma unroll
        for (int i = 0; i < 2; i++)
#pragma unroll
            for (int r = 0; r < 4; r++) {
                int lrow = i * 16 + lq * 4 + r;
                red[wid][lrow][0] = psum[i][r];
                red[wid][lrow][1] = psq[i][r];
            }
    }
    __syncthreads();
#pragma unroll
    for (int i = 0; i < 2; i++)
#pragma unroll
        for (int r = 0; r < 4; r++) {
            int lrow = i * 16 + lq * 4 + r;
            float s  = red[0][lrow][0] + red[1][lrow][0] + red[2][lrow][0] + red[3][lrow][0];
            float s2 = red[0][lrow][1] + red[1][lrow][1] + red[2][lrow][1] + red[3][lrow][1];
            float mu = s * (1.f / 256.f);
            float var = s2 * (1.f / 256.f) - mu * mu;
            float rc = rsqrtf(var + 1e-5f);
            int row = m0 + lrow;
#pragma unroll
            for (int j = 0; j < 4; j++) {
                int col = wid * 64 + j * 16 + lr;
                out[(size_t)row * 256 + col] = (acc[i][j][r] - mu) * rc * g2[col] + be2[col];
            }
        }
}

extern "C" void kernel_launch(void* const* d_in, const int* in_sizes, int n_in,
                              void* d_out, int out_size, void* d_ws, size_t ws_size,
                              hipStream_t stream) {
    const float* x   = (const float*)d_in[0];
    const int*  mask = (const int*)d_in[1];
    const float* W1  = (const float*)d_in[2];
    const float* b1  = (const float*)d_in[3];
    const float* W2  = (const float*)d_in[4];
    const float* b2  = (const float*)d_in[5];
    const float* g1  = (const float*)d_in[6];
    const float* be1 = (const float*)d_in[7];
    const float* g2  = (const float*)d_in[8];
    const float* be2 = (const float*)d_in[9];
    float* out = (float*)d_out;

    char* w = (char*)d_ws;
    unsigned short* mb_   = (unsigned short*)w;  w += 65536 * 2;                 // 128 KB
    unsigned short* E_    = (unsigned short*)w;  w += (size_t)L_ * L_ * 2;       // 8 MB
    unsigned short* XmT_  = (unsigned short*)w;  w += (size_t)1088 * L_ * 2;     // 4.25 MB
    unsigned short* W1T_  = (unsigned short*)w;  w += 262144 * 2;                // 512 KB
    unsigned short* W2T_  = (unsigned short*)w;  w += 262144 * 2;                // 512 KB
    unsigned short* Cb_   = (unsigned short*)w;  w += (size_t)L_ * 1088 * 2;     // 4.25 MB

    k_prep<<<2817, 256, 0, stream>>>(x, W1, W2, mask, mb_, XmT_, W1T_, W2T_);
    k_scores_mfma<<<dim3(32, 16), 256, 0, stream>>>(mb_, E_);
    k_av<<<272, 256, 0, stream>>>(E_, XmT_, Cb_);
    k_ffn<<<256, 256, 0, stream>>>(x, Cb_, W1T_, W2T_, b1, b2, g1, be1, g2, be2, out);
}

// Round 9
// 133.287 us; speedup vs baseline: 1.0288x; 1.0288x over previous
//
#include <hip/hip_runtime.h>
#include <hip/hip_bf16.h>

// SelfAttentionTransformer: B=4, L=2048, D=256, H=8, dk=32, F=1024
// f32 inputs / f32 output. Round 16 (= Round 15 resubmitted; container infra flake):
//  - k_ffn v3: 512 threads, producer-consumer wave specialization.
//    G1 (waves 0-3): stage W1, GEMM1+bias+relu -> t1c[2] dbuf.
//    G2 (waves 4-7): stage W2, GEMM2 on t1c[c-1], LN2 epilogue.
//    2 waves/SIMD (TLP), per-group vmcnt counting, wait-then-barrier ordering.
//  - k_prep / k_scores / k_av unchanged (R14).

#define B_ 4
#define L_ 2048
#define D_ 256
#define F_ 1024
#define PI_F 3.14159265358979323846f

typedef __bf16 bf16x8 __attribute__((ext_vector_type(8)));
typedef float floatx4 __attribute__((ext_vector_type(4)));
typedef unsigned short ushortx4 __attribute__((ext_vector_type(4)));
typedef unsigned short ushortx8 __attribute__((ext_vector_type(8)));

#define WAIT_VM(n) asm volatile("s_waitcnt vmcnt(" #n ")" ::: "memory")
#define WAIT_LGKM() asm volatile("s_waitcnt lgkmcnt(0)" ::: "memory")
#define SCHED0() __builtin_amdgcn_sched_barrier(0)
#define BARRIER() do { SCHED0(); __builtin_amdgcn_s_barrier(); SCHED0(); } while (0)

__device__ __forceinline__ unsigned short f2bf(float f) {
    unsigned int u = __float_as_uint(f);
    u = (u + 0x7FFFu + ((u >> 16) & 1u)) >> 16;   // RNE
    return (unsigned short)u;
}
__device__ __forceinline__ float bf2f(unsigned short u) {
    union { unsigned int i; float f; } v; v.i = ((unsigned int)u) << 16; return v.f;
}

__device__ __forceinline__ void async_cp16(unsigned short* lds, const unsigned short* g) {
    __builtin_amdgcn_global_load_lds(
        (const __attribute__((address_space(1))) unsigned int*)g,
        (__attribute__((address_space(3))) unsigned int*)lds, 16, 0, 0);
}

// ---------------- prep, compact 1D grid (2817 blocks) ----------------
__global__ __launch_bounds__(256) void k_prep(const float* __restrict__ x,
                                              const float* __restrict__ W1,
                                              const float* __restrict__ W2,
                                              const int* __restrict__ mask,
                                              unsigned short* __restrict__ mb,
                                              unsigned short* __restrict__ XmT,
                                              unsigned short* __restrict__ W1T,
                                              unsigned short* __restrict__ W2T) {
    __shared__ float tile[32][33];
    int r = blockIdx.x, t = threadIdx.x;
    if (r >= 2560) {
        if (r < 2816) {
            int idx = (r - 2560) * 256 + t;   // 0..65535
            int l = idx >> 5, k = idx & 31;
            float s = 0.f;
#pragma unroll
            for (int b = 0; b < B_; b++) {
                const float* xp = x + ((size_t)(b * L_ + l)) * D_ + k;
#pragma unroll
                for (int h = 0; h < 8; h++) s += xp[h * 32];
            }
            mb[idx] = f2bf(s * (1.f / 32.f));
        } else {
#pragma unroll
            for (int c = 0; c < 32; c++) {
                int e = c * 256 + t;          // 0..8191
                int b = e >> 11, j = e & (L_ - 1);
                XmT[(size_t)(1024 + b) * L_ + j] = mask[b * L_ + j] ? 0x3F80 : 0;
            }
        }
        return;
    }
    const float* in; unsigned short* outp; int R, C; const int* mrow = nullptr; size_t bo = 0;
    int bx, by;
    if (r < 2048) {
        int z = r >> 9, rem = r & 511; by = rem >> 3; bx = rem & 7;
        in = x; outp = XmT; R = L_; C = 256; bo = (size_t)z * R * C; mrow = mask + z * L_;
    } else if (r < 2304) {
        int rem = r - 2048; bx = rem & 31; by = rem >> 5;
        in = W1; outp = W1T; R = 256; C = 1024;
    } else {
        int rem = r - 2304; bx = rem & 7; by = rem >> 3;
        in = W2; outp = W2T; R = 1024; C = 256;
    }
    int r0 = by * 32, c0 = bx * 32;
    int tx = t & 31, ty = t >> 5;
#pragma unroll
    for (int rr = 0; rr < 4; rr++) {
        int rw = ty + rr * 8;
        tile[rw][tx] = in[bo + (size_t)(r0 + rw) * C + c0 + tx];
    }
    float mfac = 1.f;
    if (mrow) mfac = mrow[r0 + tx] ? 1.f : 0.f;
    __syncthreads();
#pragma unroll
    for (int rr = 0; rr < 4; rr++) {
        int c = ty + rr * 8;
        outp[bo + (size_t)(c0 + c) * R + r0 + tx] = f2bf(tile[tx][c] * mfac);
    }
}

// ---------------- E = exp(sin^2(0.5*clip(m.mT))) via MFMA, bf16 out ----------------
__global__ __launch_bounds__(256) void k_scores_mfma(const unsigned short* __restrict__ mb,
                                                     unsigned short* __restrict__ E) {
    const int t = threadIdx.x, lane = t & 63, wid = t >> 6;
    const int wm = (wid >> 1) * 64, wn = (wid & 1) * 32;
    const int lr = lane & 15, lq = lane >> 4;
    int m0 = blockIdx.y * 128, n0 = blockIdx.x * 64;
    bf16x8 af[4], bfr[2];
#pragma unroll
    for (int i = 0; i < 4; i++)
        af[i] = *(const bf16x8*)(mb + (size_t)(m0 + wm + i * 16 + lr) * 32 + lq * 8);
#pragma unroll
    for (int j = 0; j < 2; j++)
        bfr[j] = *(const bf16x8*)(mb + (size_t)(n0 + wn + j * 16 + lr) * 32 + lq * 8);
    floatx4 acc[4][2];
#pragma unroll
    for (int i = 0; i < 4; i++)
#pragma unroll
        for (int j = 0; j < 2; j++) {
            acc[i][j] = (floatx4){0.f, 0.f, 0.f, 0.f};
            acc[i][j] = __builtin_amdgcn_mfma_f32_16x16x32_bf16(af[i], bfr[j], acc[i][j], 0, 0, 0);
        }
#pragma unroll
    for (int i = 0; i < 4; i++)
#pragma unroll
        for (int j = 0; j < 2; j++)
#pragma unroll
            for (int r = 0; r < 4; r++) {
                int row = m0 + wm + i * 16 + lq * 4 + r;
                int col = n0 + wn + j * 16 + lr;
                float d = fminf(fmaxf(acc[i][j][r], -PI_F), PI_F);
                float sn = __sinf(0.5f * d);
                E[(size_t)row * L_ + col] = f2bf(__expf(sn * sn));
            }
}

// ---------------- AV: C[2048,1088] = E @ XmT^T (bf16 out), 3-deep counted-vmcnt ----------------
__global__ __launch_bounds__(256) void k_av(const unsigned short* __restrict__ E,
                                            const unsigned short* __restrict__ XmT,
                                            unsigned short* __restrict__ Cb) {
    __shared__ __align__(16) unsigned short sbuf[3][128 * 64 + 64 * 64];
    const int t = threadIdx.x, lane = t & 63, wid = t >> 6;
    const int wm = (wid >> 1) * 64, wn = (wid & 1) * 32;
    const int lr = lane & 15, lq = lane >> 4;
    const int lrow = lane >> 3, lseg = lane & 7;

    int bid = blockIdx.x;
    int swz = (bid & 7) * 34 + (bid >> 3);
    int m0 = (swz / 17) * 128, n0 = (swz % 17) * 64;

    const unsigned short* Ag[4]; int sAoff[4];
#pragma unroll
    for (int q = 0; q < 4; q++) {
        int rl = wid * 32 + q * 8 + lrow;
        Ag[q] = E + (size_t)(m0 + rl) * L_ + ((lseg - rl) & 7) * 8;
        sAoff[q] = (wid * 32 + q * 8) * 64;
    }
    const unsigned short* Bg[2]; int sBoff[2];
#pragma unroll
    for (int q = 0; q < 2; q++) {
        int rl = wid * 16 + q * 8 + lrow;
        Bg[q] = XmT + (size_t)(n0 + rl) * L_ + ((lseg - rl) & 7) * 8;
        sBoff[q] = 8192 + (wid * 16 + q * 8) * 64;
    }
    int arot[4], aroff[4], brot[2], broff[2];
#pragma unroll
    for (int i = 0; i < 4; i++) { int ar = wm + i * 16 + lr; aroff[i] = ar * 64; arot[i] = lq + ar; }
#pragma unroll
    for (int j = 0; j < 2; j++) { int br = wn + j * 16 + lr; broff[j] = 8192 + br * 64; brot[j] = lq + br; }

    floatx4 acc[4][2];
#pragma unroll
    for (int i = 0; i < 4; i++)
#pragma unroll
        for (int j = 0; j < 2; j++) acc[i][j] = (floatx4){0.f, 0.f, 0.f, 0.f};

    auto stage = [&](unsigned short* base, int k0) {
#pragma unroll
        for (int q = 0; q < 4; q++) async_cp16(base + sAoff[q], Ag[q] + k0);
#pragma unroll
        for (int q = 0; q < 2; q++) async_cp16(base + sBoff[q], Bg[q] + k0);
    };
    auto compute = [&](const unsigned short* base) {
#pragma unroll
        for (int s = 0; s < 2; s++) {
            bf16x8 af[4], bfr[2];
#pragma unroll
            for (int i = 0; i < 4; i++)
                af[i] = *(const bf16x8*)(base + aroff[i] + ((s * 4 + arot[i]) & 7) * 8);
#pragma unroll
            for (int j = 0; j < 2; j++)
                bfr[j] = *(const bf16x8*)(base + broff[j] + ((s * 4 + brot[j]) & 7) * 8);
#pragma unroll
            for (int i = 0; i < 4; i++)
#pragma unroll
                for (int j = 0; j < 2; j++)
                    acc[i][j] = __builtin_amdgcn_mfma_f32_16x16x32_bf16(af[i], bfr[j], acc[i][j], 0, 0, 0);
        }
    };

    unsigned short *p0 = sbuf[0], *p1 = sbuf[1], *p2 = sbuf[2];
    stage(p0, 0); stage(p1, 64); stage(p2, 128);
    WAIT_VM(12); BARRIER();
    for (int p = 0; p < 29; ++p) {
        compute(p0);
        BARRIER();
        stage(p0, (p + 3) << 6);
        WAIT_VM(12); BARRIER();
        unsigned short* tmp = p0; p0 = p1; p1 = p2; p2 = tmp;
    }
    compute(p0);
    BARRIER();
    WAIT_VM(6); BARRIER();
    compute(p1);
    BARRIER();
    WAIT_VM(0); BARRIER();
    compute(p2);

#pragma unroll
    for (int i = 0; i < 4; i++)
#pragma unroll
        for (int j = 0; j < 2; j++)
#pragma unroll
            for (int r = 0; r < 4; r++) {
                int row = m0 + wm + i * 16 + lq * 4 + r;
                int col = n0 + wn + j * 16 + lr;
                Cb[(size_t)row * 1088 + col] = f2bf(acc[i][j][r]);
            }
}

// ---------------- k_ffn v3: producer-consumer, 512 threads ----------------
// out = LN2( h + relu(h@W1+b1)@W2 + b2 ),  h = LN1(x + C/rs)
// G1 (waves 0-3): GEMM1 -> t1c[2];  G2 (waves 4-7): GEMM2 + LN2
__global__ __launch_bounds__(512, 1) void k_ffn(const float* __restrict__ x,
                                                const unsigned short* __restrict__ Cb,
                                                const unsigned short* __restrict__ W1T,
                                                const unsigned short* __restrict__ W2T,
                                                const float* __restrict__ b1,
                                                const float* __restrict__ b2,
                                                const float* __restrict__ g1, const float* __restrict__ be1,
                                                const float* __restrict__ g2, const float* __restrict__ be2,
                                                float* __restrict__ out) {
    __shared__ __align__(16) unsigned short hA[4 * 32 * 64];        // 16 KB
    __shared__ __align__(16) unsigned short W1b[2][4 * 64 * 64];    // 64 KB
    __shared__ __align__(16) unsigned short W2b[2][4 * 64 * 64];    // 64 KB
    __shared__ __align__(16) unsigned short t1c[2][32 * 72];        // 9 KB
    __shared__ float b1s[1024];                                     // 4 KB
    __shared__ float red[4][32][2];                                 // 1 KB  => 158 KB

    const int t = threadIdx.x, lane = t & 63, wid = t >> 6;         // wid 0..7
    const bool isG1 = wid < 4;
    const int gw = wid & 3;
    const int lr = lane & 15, lq = lane >> 4;
    const int half = lane >> 5, l32 = lane & 31;
    const int lrow8 = lane >> 3, kk = lane & 7;
    const int m0 = blockIdx.x * 32;

    // G1-only stage: W1 chunk fc (64 f-cols), layout [kc][fl][rot-slot]
    auto stageW1 = [&](unsigned short* buf, int fc) {
#pragma unroll
        for (int q = 0; q < 8; q++) {
            int kc = q >> 1, sub = q & 1;
            int fl = sub * 32 + gw * 8 + lrow8;
            const unsigned short* src = W1T + (size_t)(fc * 64 + fl) * 256 + kc * 64 + (((kk - fl) & 7) * 8);
            async_cp16(buf + kc * 4096 + sub * 2048 + gw * 512, src);
        }
    };
    // G2-only stage: W2 chunk fc (64 k-rows), layout [nc][nl][rot-slot]
    auto stageW2 = [&](unsigned short* buf, int fc) {
#pragma unroll
        for (int q = 0; q < 8; q++) {
            int nc = q >> 1, sub = q & 1;
            int nl = sub * 32 + gw * 8 + lrow8;
            const unsigned short* src = W2T + (size_t)(nc * 64 + nl) * 1024 + fc * 64 + (((kk - nl) & 7) * 8);
            async_cp16(buf + nc * 4096 + sub * 2048 + gw * 512, src);
        }
    };

    // prologue stages (per-group counters)
    if (isG1) { stageW1(W1b[0], 0); stageW1(W1b[1], 1); }
    else      { stageW2(W2b[0], 0); stageW2(W2b[1], 1); }

    // b1 -> LDS (2 loads/thread)
    b1s[t] = b1[t];
    b1s[512 + t] = b1[512 + t];
    float4 g1a = *(const float4*)(g1 + l32 * 8);
    float4 g1b = *(const float4*)(g1 + l32 * 8 + 4);
    float4 be1a = *(const float4*)(be1 + l32 * 8);
    float4 be1b = *(const float4*)(be1 + l32 * 8 + 4);

    // ---- LN1: h[32][256] -> hA (rotate-swizzled), 4 tokens/wave ----
#pragma unroll
    for (int it = 0; it < 2; it++) {
        int tloc = wid * 4 + it * 2 + half;
        int tok = m0 + tloc;
        int bi = tok >> 11, ii = tok & (L_ - 1);
        float rs = bf2f(Cb[(size_t)ii * 1088 + 1024 + bi]);
        float4 xv0 = *(const float4*)(x + (size_t)tok * D_ + l32 * 8);
        float4 xv1 = *(const float4*)(x + (size_t)tok * D_ + l32 * 8 + 4);
        ushortx8 cv = *(const ushortx8*)(Cb + (size_t)ii * 1088 + bi * 256 + l32 * 8);
        float v[8];
        v[0] = xv0.x + bf2f(cv[0]) / rs; v[1] = xv0.y + bf2f(cv[1]) / rs;
        v[2] = xv0.z + bf2f(cv[2]) / rs; v[3] = xv0.w + bf2f(cv[3]) / rs;
        v[4] = xv1.x + bf2f(cv[4]) / rs; v[5] = xv1.y + bf2f(cv[5]) / rs;
        v[6] = xv1.z + bf2f(cv[6]) / rs; v[7] = xv1.w + bf2f(cv[7]) / rs;
        float s = 0.f, s2 = 0.f;
#pragma unroll
        for (int k = 0; k < 8; k++) { s += v[k]; s2 += v[k] * v[k]; }
#pragma unroll
        for (int o = 1; o < 32; o <<= 1) { s += __shfl_xor(s, o); s2 += __shfl_xor(s2, o); }
        float mu = s * (1.f / 256.f);
        float var = s2 * (1.f / 256.f) - mu * mu;
        float rq = rsqrtf(var + 1e-5f);
        union { bf16x8 v8; unsigned short u[8]; } hv;
        hv.u[0] = f2bf((v[0] - mu) * rq * g1a.x + be1a.x);
        hv.u[1] = f2bf((v[1] - mu) * rq * g1a.y + be1a.y);
        hv.u[2] = f2bf((v[2] - mu) * rq * g1a.z + be1a.z);
        hv.u[3] = f2bf((v[3] - mu) * rq * g1a.w + be1a.w);
        hv.u[4] = f2bf((v[4] - mu) * rq * g1b.x + be1b.x);
        hv.u[5] = f2bf((v[5] - mu) * rq * g1b.y + be1b.y);
        hv.u[6] = f2bf((v[6] - mu) * rq * g1b.z + be1b.z);
        hv.u[7] = f2bf((v[7] - mu) * rq * g1b.w + be1b.w);
        *(bf16x8*)(hA + (l32 >> 3) * 2048 + tloc * 64 + ((((l32 & 7) + tloc) & 7) * 8)) = hv.v8;
    }
    WAIT_VM(0); WAIT_LGKM(); BARRIER();   // hA + b1s published; prologue W loads landed; vmcnt=0 all waves

    // ---- G1: hoist h A-fragments ----
    bf16x8 haf[2][8];
    if (isG1) {
#pragma unroll
        for (int i = 0; i < 2; i++)
#pragma unroll
            for (int kc = 0; kc < 4; kc++)
#pragma unroll
                for (int s = 0; s < 2; s++) {
                    int row = i * 16 + lr;
                    haf[i][kc * 2 + s] = *(const bf16x8*)(hA + kc * 2048 + row * 64 + (((s * 4 + lq + row) & 7) * 8));
                }
    }

    floatx4 acc[2][4];
#pragma unroll
    for (int i = 0; i < 2; i++)
#pragma unroll
        for (int j = 0; j < 4; j++) acc[i][j] = (floatx4){0.f, 0.f, 0.f, 0.f};

    const int wcol = gw * 16 + lr;        // G1: local f col

    // ---- pipelined loop: G1 runs chunk cc (0..15), G2 runs chunk cc-1 ----
#pragma unroll 1
    for (int cc = 0; cc <= 16; ++cc) {
        if (cc >= 15) { WAIT_VM(0); } else { WAIT_VM(8); }   // own-group W(cur) landed
        BARRIER();                                            // publish W stages + t1c(prev)
        if (isG1) {
            if (cc < 16) {
                const unsigned short* w1cur = W1b[cc & 1];
                floatx4 a1[2] = { (floatx4){0.f,0.f,0.f,0.f}, (floatx4){0.f,0.f,0.f,0.f} };
#pragma unroll
                for (int kc = 0; kc < 4; kc++)
#pragma unroll
                    for (int s = 0; s < 2; s++) {
                        bf16x8 bfr = *(const bf16x8*)(w1cur + kc * 4096 + wcol * 64 + (((s * 4 + lq + wcol) & 7) * 8));
                        a1[0] = __builtin_amdgcn_mfma_f32_16x16x32_bf16(haf[0][kc * 2 + s], bfr, a1[0], 0, 0, 0);
                        a1[1] = __builtin_amdgcn_mfma_f32_16x16x32_bf16(haf[1][kc * 2 + s], bfr, a1[1], 0, 0, 0);
                    }
                float bv = b1s[cc * 64 + wcol];
                unsigned short* tc = t1c[cc & 1];
#pragma unroll
                for (int i = 0; i < 2; i++)
#pragma unroll
                    for (int r = 0; r < 4; r++)
                        tc[(i * 16 + lq * 4 + r) * 72 + wcol] = f2bf(fmaxf(a1[i][r] + bv, 0.f));
                WAIT_LGKM();
            }
        } else {
            if (cc >= 1) {
                int d = cc - 1;
                const unsigned short* w2cur = W2b[d & 1];
                const unsigned short* tc = t1c[d & 1];
#pragma unroll
                for (int s = 0; s < 2; s++) {
                    bf16x8 af0 = *(const bf16x8*)(tc + lr * 72 + s * 32 + lq * 8);
                    bf16x8 af1 = *(const bf16x8*)(tc + (16 + lr) * 72 + s * 32 + lq * 8);
#pragma unroll
                    for (int j = 0; j < 4; j++) {
                        int nl = j * 16 + lr;
                        bf16x8 bfr = *(const bf16x8*)(w2cur + gw * 4096 + nl * 64 + (((s * 4 + lq + nl) & 7) * 8));
                        acc[0][j] = __builtin_amdgcn_mfma_f32_16x16x32_bf16(af0, bfr, acc[0][j], 0, 0, 0);
                        acc[1][j] = __builtin_amdgcn_mfma_f32_16x16x32_bf16(af1, bfr, acc[1][j], 0, 0, 0);
                    }
                }
            }
        }
        BARRIER();                                            // all reads of W(cur)/t1c done
        if (isG1) {
            if (cc <= 13) stageW1(W1b[cc & 1], cc + 2);       // W1(cc+2)
        } else {
            if (cc >= 1 && cc <= 14) stageW2(W2b[(cc - 1) & 1], cc + 1);  // W2(cc+1)
        }
    }

    // ---- LN2 epilogue (G2 only computes; all waves pass barriers) ----
    float psum[2][4], psq[2][4];
#pragma unroll
    for (int i = 0; i < 2; i++)
#pragma unroll
        for (int r = 0; r < 4; r++) { psum[i][r] = 0.f; psq[i][r] = 0.f; }
    if (!isG1) {
#pragma unroll
        for (int i = 0; i < 2; i++)
#pragma unroll
            for (int j = 0; j < 4; j++) {
                int col = gw * 64 + j * 16 + lr;
                float bv = b2[col];
                int kc = col >> 6, ks = (col >> 3) & 7, ke = col & 7;
#pragma unroll
                for (int r = 0; r < 4; r++) {
                    int row = i * 16 + lq * 4 + r;
                    float hres = bf2f(hA[kc * 2048 + row * 64 + (((ks + row) & 7) * 8) + ke]);
                    float v = acc[i][j][r] + bv + hres;
                    acc[i][j][r] = v;
                    psum[i][r] += v; psq[i][r] += v * v;
                }
            }
#pragma unroll
        for (int o = 1; o < 16; o <<= 1)
#pragma unroll
            for (int i = 0; i < 2; i++)
#pragma unroll
                for (int r = 0; r < 4; r++) { psum[i][r] += __shfl_xor(psum[i][r], o); psq[i][r] += __shfl_xor(psq[i][r], o); }
        if (lr == 0) {
#pragma unroll
            for (int i = 0; i < 2; i++)
#pragma unroll
                for (int r = 0; r < 4; r++) {
                    int lrow = i * 16 + lq * 4 + r;
                    red[gw][lrow][0] = psum[i][r];
                    red[gw][lrow][1] = psq[i][r];
                }
        }
    }
    __syncthreads();
    if (!isG1) {
#pragma unroll
        for (int i = 0; i < 2; i++)
#pragma unroll
            for (int r = 0; r < 4; r++) {
                int lrow = i * 16 + lq * 4 + r;
                float s  = red[0][lrow][0] + red[1][lrow][0] + red[2][lrow][0] + red[3][lrow][0];
                float s2 = red[0][lrow][1] + red[1][lrow][1] + red[2][lrow][1] + red[3][lrow][1];
                float mu = s * (1.f / 256.f);
                float var = s2 * (1.f / 256.f) - mu * mu;
                float rc = rsqrtf(var + 1e-5f);
                int row = m0 + lrow;
#pragma unroll
                for (int j = 0; j < 4; j++) {
                    int col = gw * 64 + j * 16 + lr;
                    out[(size_t)row * 256 + col] = (acc[i][j][r] - mu) * rc * g2[col] + be2[col];
                }
            }
    }
}

extern "C" void kernel_launch(void* const* d_in, const int* in_sizes, int n_in,
                              void* d_out, int out_size, void* d_ws, size_t ws_size,
                              hipStream_t stream) {
    const float* x   = (const float*)d_in[0];
    const int*  mask = (const int*)d_in[1];
    const float* W1  = (const float*)d_in[2];
    const float* b1  = (const float*)d_in[3];
    const float* W2  = (const float*)d_in[4];
    const float* b2  = (const float*)d_in[5];
    const float* g1  = (const float*)d_in[6];
    const float* be1 = (const float*)d_in[7];
    const float* g2  = (const float*)d_in[8];
    const float* be2 = (const float*)d_in[9];
    float* out = (float*)d_out;

    char* w = (char*)d_ws;
    unsigned short* mb_   = (unsigned short*)w;  w += 65536 * 2;                 // 128 KB
    unsigned short* E_    = (unsigned short*)w;  w += (size_t)L_ * L_ * 2;       // 8 MB
    unsigned short* XmT_  = (unsigned short*)w;  w += (size_t)1088 * L_ * 2;     // 4.25 MB
    unsigned short* W1T_  = (unsigned short*)w;  w += 262144 * 2;                // 512 KB
    unsigned short* W2T_  = (unsigned short*)w;  w += 262144 * 2;                // 512 KB
    unsigned short* Cb_   = (unsigned short*)w;  w += (size_t)L_ * 1088 * 2;     // 4.25 MB

    k_prep<<<2817, 256, 0, stream>>>(x, W1, W2, mask, mb_, XmT_, W1T_, W2T_);
    k_scores_mfma<<<dim3(32, 16), 256, 0, stream>>>(mb_, E_);
    k_av<<<272, 256, 0, stream>>>(E_, XmT_, Cb_);
    k_ffn<<<256, 512, 0, stream>>>(x, Cb_, W1T_, W2T_, b1, b2, g1, be1, g2, be2, out);
}